// Round 8
// baseline (471.030 us; speedup 1.0000x reference)
//
#include <hip/hip_runtime.h>

// EGNN layer (round 17): recombine TLP (16 waves) with pipeline+hoists.
//  - r16: balance fix + launch trims = flat. edge still 196us, VALU 59%.
//  - Ledger arithmetic: r10 spilled at 16 waves because pipeline needed ~130-150
//    regs vs the 128/wave budget (4 waves/SIMD). r15's hoists cut measured arch
//    VGPR to 84 -> 84 arch + 32 acc = 116 <= 128. Pipeline+hoists now FIT at
//    16 waves/CU. This round: NW 12->16 (1024 thr, launch_bounds(1024,4)),
//    loop byte-identical. Expect VALUBusy 59->~72, edge ~165-175us.
//  - No-spill check: VGPR<=96 AND FETCH ~98MB. VGPR=96 + FETCH inflation =>
//    spill => revert to NW=12 next round.
//  - Also: scan3 deleted; place_k adds the 49-block bsum prefix inline
//    (one-wave shfl prefix, +pref[row>>10] on the atomic position).
//  - Kept: reg pipeline, invariant hoists, setprio, proportional split,
//    pre_k fusion (transpose+hist), shfl scan1.

#define NN 50000
#define NE 800000
#define LDST 136
#define NW 16
#define NSTRIPE (NE / 16)
#define EGRID 256
#define NWG (EGRID * NW)  // 4096 wave-groups
#define NB 49             // scan blocks (1024 elems each)

typedef __bf16 bf16_t;
typedef __bf16 bf16x8 __attribute__((ext_vector_type(8)));
typedef float f32x4 __attribute__((ext_vector_type(4)));

__device__ __forceinline__ float fsilu(float z) {
  return z * __builtin_amdgcn_rcpf(1.f + __expf(-z));
}
__device__ __forceinline__ float fsigm(float z) {
  return __builtin_amdgcn_rcpf(1.f + __expf(-z));
}

__device__ __forceinline__ void gemm_stripe(const bf16_t* Arow, const bf16_t* Bcol,
                                            int koff, f32x4 acc[8]) {
#pragma unroll
  for (int ks = 0; ks < 4; ++ks) {
    bf16x8 a = *(const bf16x8*)(Arow + ks * 32 + koff);
#pragma unroll
    for (int nt = 0; nt < 8; ++nt) {
      bf16x8 b = *(const bf16x8*)(Bcol + nt * 16 * LDST + ks * 32 + koff);
      acc[nt] = __builtin_amdgcn_mfma_f32_16x16x32_bf16(a, b, acc[nt], 0, 0, 0);
    }
  }
}

__device__ __forceinline__ void load_B(bf16_t* Bsb, const bf16_t* __restrict__ src, int t) {
  for (int i = t; i < 2048; i += 256) {
    int n = i >> 4, cc = i & 15;
    *(bf16x8*)(Bsb + n * LDST + cc * 8) = *(const bf16x8*)(src + n * 128 + cc * 8);
  }
}

__device__ __forceinline__ bf16x8 cvt8(float4 u0, float4 u1) {
  bf16x8 v;
  v[0] = (bf16_t)u0.x; v[1] = (bf16_t)u0.y; v[2] = (bf16_t)u0.z; v[3] = (bf16_t)u0.w;
  v[4] = (bf16_t)u1.x; v[5] = (bf16_t)u1.y; v[6] = (bf16_t)u1.z; v[7] = (bf16_t)u1.w;
  return v;
}

// ---- pre_k: fused weight transpose (blocks 0..111) + degree hist (112..) ----
__global__ __launch_bounds__(256) void pre_k(
    const float* __restrict__ e_w1, const float* __restrict__ e_w2,
    const float* __restrict__ n_w1, const float* __restrict__ n_w2,
    const float* __restrict__ c_w1, bf16_t* __restrict__ wt,
    const int* __restrict__ ei, int* __restrict__ deg) {
  int b = blockIdx.x;
  if (b < 112) {
    int slot = b >> 4;
    int sub = b & 15;
    const float* src;
    switch (slot) {
      case 0: src = e_w1; break;
      case 1: src = e_w1 + 16384; break;
      case 2: src = e_w2; break;
      case 3: src = n_w1; break;
      case 4: src = n_w1 + 16384; break;
      case 5: src = n_w2; break;
      default: src = c_w1; break;
    }
    bf16_t* dst = wt + slot * 16384;
    int base = sub * 1024;
    for (int i = base + threadIdx.x; i < base + 1024; i += 256) {
      int k = i >> 7, n = i & 127;
      dst[n * 128 + k] = (bf16_t)src[k * 128 + n];
    }
  } else {
    int e = (b - 112) * 256 + threadIdx.x;
    if (e < NE) atomicAdd(&deg[ei[e]], 1);
  }
}

// ---- prep: pa = bf16(h@W1a + e_b1), pb = bf16(h@W1b) ----
__global__ __launch_bounds__(256) void prep_k(
    const float* __restrict__ h, const bf16_t* __restrict__ wt,
    const float* __restrict__ e_b1, bf16_t* __restrict__ pa, bf16_t* __restrict__ pb) {
  __shared__ __align__(16) bf16_t Asb[64 * LDST];
  __shared__ __align__(16) bf16_t Bsb[128 * LDST];
  int t = threadIdx.x;
  int node0 = blockIdx.x * 64;
  for (int i = t; i < 1024; i += 256) {
    int rowl = i >> 4, cc = i & 15;
    int node = node0 + rowl; if (node >= NN) node = NN - 1;
    const float4* p = (const float4*)(h + (size_t)node * 128 + cc * 8);
    *(bf16x8*)(Asb + rowl * LDST + cc * 8) = cvt8(p[0], p[1]);
  }
  int lane = t & 63, w = t >> 6;
  int m0 = w * 16, quad = lane >> 4, cix = lane & 15, koff = quad * 8;
  const bf16_t* Arow = Asb + (m0 + cix) * LDST;
  const bf16_t* Bcol = Bsb + cix * LDST;

  bf16_t* outp[2] = {pa, pb};
#pragma unroll
  for (int p = 0; p < 2; ++p) {
    __syncthreads();
    load_B(Bsb, wt + p * 16384, t);
    __syncthreads();
    f32x4 acc[8];
#pragma unroll
    for (int i = 0; i < 8; ++i) acc[i] = (f32x4){0.f, 0.f, 0.f, 0.f};
    gemm_stripe(Arow, Bcol, koff, acc);
#pragma unroll
    for (int nt = 0; nt < 8; ++nt) {
      int colg = nt * 16 + cix;
      float bv = p == 0 ? e_b1[colg] : 0.f;
#pragma unroll
      for (int rix = 0; rix < 4; ++rix) {
        int node = node0 + m0 + quad * 4 + rix;
        if (node < NN) outp[p][(size_t)node * 128 + colg] = (bf16_t)(acc[nt][rix] + bv);
      }
    }
  }
}

// ---- scan1: shfl-based wave scan (2 barriers) ----
__global__ __launch_bounds__(1024) void scan1_k(const int* __restrict__ deg,
                                                int* __restrict__ curs,
                                                int* __restrict__ bsum) {
  __shared__ int wsum[16];
  int t = threadIdx.x;
  int lane = t & 63, wv = t >> 6;
  int i = blockIdx.x * 1024 + t;
  int v = (i < NN) ? deg[i] : 0;
  int sc = v;
#pragma unroll
  for (int off = 1; off < 64; off <<= 1) {
    int u = __shfl_up(sc, off);
    if (lane >= off) sc += u;
  }
  if (lane == 63) wsum[wv] = sc;
  __syncthreads();
  if (wv == 0 && lane < 16) {
    int ws = wsum[lane];
#pragma unroll
    for (int off = 1; off < 16; off <<= 1) {
      int u = __shfl_up(ws, off, 16);
      if ((lane & 15) >= off) ws += u;
    }
    wsum[lane] = ws;
  }
  __syncthreads();
  int base = (wv > 0) ? wsum[wv - 1] : 0;
  int incl = base + sc;
  if (i < NN) curs[i] = incl - v;  // exclusive within block
  if (t == 1023) bsum[blockIdx.x] = incl;
}

// ---- place: scatter packed records; block-prefix of bsum computed inline ----
__global__ __launch_bounds__(256) void place_k(const int* __restrict__ ei,
                                               const float* __restrict__ eattr,
                                               int* __restrict__ curs,
                                               const int* __restrict__ bsum,
                                               int2* __restrict__ rec) {
  __shared__ int pref[64];
  int t = threadIdx.x;
  if (t < 64) {
    int v = (t < NB) ? bsum[t] : 0;
    int sc = v;
#pragma unroll
    for (int off = 1; off < 64; off <<= 1) {
      int u = __shfl_up(sc, off);
      if (t >= off) sc += u;
    }
    pref[t] = sc - v;  // exclusive prefix across scan blocks
  }
  __syncthreads();
  int e = blockIdx.x * 256 + t;
  if (e < NE) {
    int row = ei[e];
    int col = ei[NE + e];
    int pos = atomicAdd(&curs[row], 1) + pref[row >> 10];
    int2 rv;
    rv.x = (int)((unsigned)row * 50000u + (unsigned)col);
    rv.y = __float_as_int(eattr[e]);
    rec[pos] = rv;
  }
}

// ---- edge kernel: 16 waves/CU, register pipeline + invariant hoists ----
// Budget: 4 waves/SIMD -> 128 total/wave; measured demand 84 arch + 32 acc = 116.
__global__ __launch_bounds__(1024, 4) void edge_k(
    const bf16_t* __restrict__ pa, const bf16_t* __restrict__ pb,
    const int2* __restrict__ rec, const float* __restrict__ x,
    const bf16_t* __restrict__ wt, const float* __restrict__ e_w1,
    const float* __restrict__ e_b2, const float* __restrict__ c_b1,
    const float* __restrict__ c_w2, const float* __restrict__ a_w,
    const float* __restrict__ a_b, float* __restrict__ agg,
    float* __restrict__ coord_agg) {
  __shared__ __align__(16) bf16_t Bs2[16384];          // e_w2 (MFMA-chunk layout)
  __shared__ __align__(16) bf16_t Bs6[16384];          // c_w1
  __shared__ __align__(16) float Wr[128];              // w_rad row (loop-invariant)
  __shared__ __align__(16) float We[128];              // w_ea row
  __shared__ __align__(16) bf16_t Ag[NW * 16 * LDST];  // per-wave m stripes

  int t = threadIdx.x;
  const float* wrp = e_w1 + 256 * 128;
  const float* wep = e_w1 + 257 * 128;
  if (t < 128) Wr[t] = wrp[t];
  else if (t < 256) We[t - 128] = wep[t - 128];
  for (int cch = t; cch < 2048; cch += 1024) {
    int nt = cch >> 8, rem = cch & 255, kc = rem >> 4, ci = rem & 15;
    int n = nt * 16 + ci;
    *(bf16x8*)(Bs2 + cch * 8) = *(const bf16x8*)(wt + 2 * 16384 + n * 128 + kc * 8);
    *(bf16x8*)(Bs6 + cch * 8) = *(const bf16x8*)(wt + 6 * 16384 + n * 128 + kc * 8);
  }
  __syncthreads();  // the only barrier

  int lane = t & 63, w = t >> 6;
  int quad = lane >> 4, cix = lane & 15, koff = quad * 8;
  bf16_t* Aw = Ag + w * (16 * LDST);
  float a_bv = a_b[0];

  // loop-invariant per-lane epilogue constants (32 VGPRs; unrolled-index only)
  float eb2v[8], awv8[8], cb1v8[8], cw2v8[8];
#pragma unroll
  for (int nt = 0; nt < 8; ++nt) {
    int colg = nt * 16 + cix;
    eb2v[nt] = e_b2[colg];
    awv8[nt] = a_w[colg];
    cb1v8[nt] = c_b1[colg];
    cw2v8[nt] = c_w2[colg];
  }

  // proportional split: every wave gets 12 or 13 stripes
  int wg = blockIdx.x * NW + w;
  int s0 = (int)(((long long)wg * NSTRIPE) / NWG);
  int s1 = (int)(((long long)(wg + 1) * NSTRIPE) / NWG);

  // carried run state (wave-uniform currow; per-lane col sums)
  int currow = -1;
  int col = 2 * lane;
  float sa = 0.f, sb = 0.f, c0 = 0.f, c1 = 0.f, c2 = 0.f;

  if (s0 < s1) {
    // ---- prologue: fully load stripe s0 into registers ----
    int2 rv = rec[s0 * 16 + cix];
    unsigned rcu = (unsigned)rv.x;
    int r = (int)(rcu / 50000u);
    int c = (int)(rcu - (unsigned)r * 50000u);
    float ea = __int_as_float(rv.y);
    float d0 = x[r * 3 + 0] - x[c * 3 + 0];
    float d1 = x[r * 3 + 1] - x[c * 3 + 1];
    float d2 = x[r * 3 + 2] - x[c * 3 + 2];
    float rad = d0 * d0 + d1 * d1 + d2 * d2;
    bf16x8 pa8[4], pb8[4];
    {
      const bf16_t* par = pa + (size_t)r * 128;
      const bf16_t* pbr = pb + (size_t)c * 128;
#pragma unroll
      for (int ks = 0; ks < 4; ++ks) {
        pa8[ks] = *(const bf16x8*)(par + ks * 32 + koff);
        pb8[ks] = *(const bf16x8*)(pbr + ks * 32 + koff);
      }
    }

#pragma unroll 1
    for (int s = s0; s < s1; ++s) {
      // (1) prefetch next stripe's record
      int sn = (s + 1 < s1) ? s + 1 : s;
      int2 rvn = rec[sn * 16 + cix];

      // (2) GEMM1 fused on CURRENT regs:
      //     z1 = silu(pa[r]+pb[c]+rad*w_rad+ea*w_ea) as A-frag; C = z1 @ e_w2
      f32x4 acc[8];
#pragma unroll
      for (int i = 0; i < 8; ++i) acc[i] = (f32x4){0.f, 0.f, 0.f, 0.f};
#pragma unroll
      for (int ks = 0; ks < 4; ++ks) {
        int kk = ks * 32 + koff;
        float4 wr0 = *(const float4*)(Wr + kk);
        float4 wr1 = *(const float4*)(Wr + kk + 4);
        float4 we0 = *(const float4*)(We + kk);
        float4 we1 = *(const float4*)(We + kk + 4);
        float wrv[8] = {wr0.x, wr0.y, wr0.z, wr0.w, wr1.x, wr1.y, wr1.z, wr1.w};
        float wev[8] = {we0.x, we0.y, we0.z, we0.w, we1.x, we1.y, we1.z, we1.w};
        bf16x8 af;
#pragma unroll
        for (int j = 0; j < 8; ++j) {
          float z = (float)pa8[ks][j] + (float)pb8[ks][j] + rad * wrv[j] + ea * wev[j];
          af[j] = (bf16_t)fsilu(z);
        }
        __builtin_amdgcn_s_setprio(1);
#pragma unroll
        for (int nt = 0; nt < 8; ++nt) {
          bf16x8 b = *(const bf16x8*)(Bs2 + (nt * 256 + (ks * 4 + quad) * 16 + cix) * 8);
          acc[nt] = __builtin_amdgcn_mfma_f32_16x16x32_bf16(af, b, acc[nt], 0, 0, 0);
        }
        __builtin_amdgcn_s_setprio(0);
      }

      // (3) decode NEXT record, issue its gathers now
      unsigned rcn = (unsigned)rvn.x;
      int rn = (int)(rcn / 50000u);
      int cn = (int)(rcn - (unsigned)rn * 50000u);
      float ean = __int_as_float(rvn.y);
      float xr0n = x[rn * 3 + 0], xr1n = x[rn * 3 + 1], xr2n = x[rn * 3 + 2];
      float xc0n = x[cn * 3 + 0], xc1n = x[cn * 3 + 1], xc2n = x[cn * 3 + 2];
      bf16x8 pa8n[4], pb8n[4];
      {
        const bf16_t* parn = pa + (size_t)rn * 128;
        const bf16_t* pbrn = pb + (size_t)cn * 128;
#pragma unroll
        for (int ks = 0; ks < 4; ++ks) {
          pa8n[ks] = *(const bf16x8*)(parn + ks * 32 + koff);
          pb8n[ks] = *(const bf16x8*)(pbrn + ks * 32 + koff);
        }
      }

      // (4) epilogue 1: m = silu(.+b2); att = sigmoid(m.a_w+a_b); m *= att; m -> Aw
      float attp[4] = {0.f, 0.f, 0.f, 0.f};
#pragma unroll
      for (int nt = 0; nt < 8; ++nt) {
        float b2v = eb2v[nt];
        float awv = awv8[nt];
#pragma unroll
        for (int rix = 0; rix < 4; ++rix) {
          float v = fsilu(acc[nt][rix] + b2v);
          acc[nt][rix] = v;
          attp[rix] += v * awv;
        }
      }
      float attv[4];
#pragma unroll
      for (int rix = 0; rix < 4; ++rix) {
        float sv = attp[rix];
        sv += __shfl_xor(sv, 1); sv += __shfl_xor(sv, 2);
        sv += __shfl_xor(sv, 4); sv += __shfl_xor(sv, 8);
        attv[rix] = fsigm(sv + a_bv);
      }
#pragma unroll
      for (int nt = 0; nt < 8; ++nt) {
#pragma unroll
        for (int rix = 0; rix < 4; ++rix) {
          float v = acc[nt][rix] * attv[rix];
          Aw[(quad * 4 + rix) * LDST + nt * 16 + cix] = (bf16_t)v;
        }
      }

      // (5) GEMM2: coord_update = silu(m @ c_w1 + c_b1) . c_w2 (wave-local LDS RAW)
      const bf16_t* Arow = Aw + cix * LDST;
#pragma unroll
      for (int i = 0; i < 8; ++i) acc[i] = (f32x4){0.f, 0.f, 0.f, 0.f};
#pragma unroll
      for (int ks = 0; ks < 4; ++ks) {
        bf16x8 a = *(const bf16x8*)(Arow + ks * 32 + koff);
        __builtin_amdgcn_s_setprio(1);
#pragma unroll
        for (int nt = 0; nt < 8; ++nt) {
          bf16x8 b = *(const bf16x8*)(Bs6 + (nt * 256 + (ks * 4 + quad) * 16 + cix) * 8);
          acc[nt] = __builtin_amdgcn_mfma_f32_16x16x32_bf16(a, b, acc[nt], 0, 0, 0);
        }
        __builtin_amdgcn_s_setprio(0);
      }
      float cup[4] = {0.f, 0.f, 0.f, 0.f};
#pragma unroll
      for (int nt = 0; nt < 8; ++nt) {
        float cb1v = cb1v8[nt];
        float cw2v = cw2v8[nt];
#pragma unroll
        for (int rix = 0; rix < 4; ++rix) {
          cup[rix] += fsilu(acc[nt][rix] + cb1v) * cw2v;
        }
      }
#pragma unroll
      for (int rix = 0; rix < 4; ++rix) {
        float sv = cup[rix];
        sv += __shfl_xor(sv, 1); sv += __shfl_xor(sv, 2);
        sv += __shfl_xor(sv, 4); sv += __shfl_xor(sv, 8);
        cup[rix] = sv;  // all 16 lanes of the quad hold that edge's scalar
      }

      // (6) carried-run merge: flush only on row change (runs span stripes)
#pragma unroll
      for (int e = 0; e < 16; ++e) {
        int rowe = __shfl(r, e);
        if (rowe != currow) {
          if (currow >= 0) {
            atomicAdd(&agg[(size_t)currow * 128 + col], sa);
            atomicAdd(&agg[(size_t)currow * 128 + col + 1], sb);
            if (lane == 0) {
              atomicAdd(&coord_agg[currow * 3 + 0], c0);
              atomicAdd(&coord_agg[currow * 3 + 1], c1);
              atomicAdd(&coord_agg[currow * 3 + 2], c2);
            }
          }
          sa = sb = c0 = c1 = c2 = 0.f;
          currow = rowe;
        }
        float cue = __shfl(cup[e & 3], (e >> 2) * 16);
        float dd0 = __shfl(d0, e), dd1 = __shfl(d1, e), dd2 = __shfl(d2, e);
        c0 += dd0 * cue; c1 += dd1 * cue; c2 += dd2 * cue;
        unsigned u = *(const unsigned*)(Aw + e * LDST + col);
        sa += __uint_as_float(u << 16);
        sb += __uint_as_float(u & 0xffff0000u);
      }

      // (7) rotate: next becomes current
      r = rn; ea = ean;
      d0 = xr0n - xc0n; d1 = xr1n - xc1n; d2 = xr2n - xc2n;
      rad = d0 * d0 + d1 * d1 + d2 * d2;
#pragma unroll
      for (int ks = 0; ks < 4; ++ks) { pa8[ks] = pa8n[ks]; pb8[ks] = pb8n[ks]; }
    }
  }

  // final flush
  if (currow >= 0) {
    atomicAdd(&agg[(size_t)currow * 128 + col], sa);
    atomicAdd(&agg[(size_t)currow * 128 + col + 1], sb);
    if (lane == 0) {
      atomicAdd(&coord_agg[currow * 3 + 0], c0);
      atomicAdd(&coord_agg[currow * 3 + 1], c1);
      atomicAdd(&coord_agg[currow * 3 + 2], c2);
    }
  }
}

// ---- node kernel (in-place on d_out) ----
__global__ __launch_bounds__(256) void node_k(
    const float* __restrict__ h, const float* __restrict__ x,
    const bf16_t* __restrict__ wt, const float* __restrict__ n_b1,
    const float* __restrict__ n_b2, const int* __restrict__ deg,
    float* __restrict__ out) {
  __shared__ __align__(16) bf16_t Asb[64 * LDST];
  __shared__ __align__(16) bf16_t Bsb[128 * LDST];
  int t = threadIdx.x;
  int node0 = blockIdx.x * 64;
  const float* agg = out;
  float* xout = out + (size_t)NN * 128;

  if (t < 192) {
    int node = node0 + t / 3;
    int d = t - (t / 3) * 3;
    if (node < NN) {
      int dv = deg[node];
      float denom = dv > 1 ? (float)dv : 1.f;
      float xo = x[node * 3 + d] + xout[node * 3 + d] / denom;
      xout[node * 3 + d] = xo;
    }
  }

  for (int i = t; i < 1024; i += 256) {
    int rowl = i >> 4, cc = i & 15;
    int node = node0 + rowl; if (node >= NN) node = NN - 1;
    const float4* p = (const float4*)(h + (size_t)node * 128 + cc * 8);
    *(bf16x8*)(Asb + rowl * LDST + cc * 8) = cvt8(p[0], p[1]);
  }
  load_B(Bsb, wt + 3 * 16384, t);  // n_w1a_t
  __syncthreads();

  int lane = t & 63, w = t >> 6;
  int m0 = w * 16, quad = lane >> 4, cix = lane & 15, koff = quad * 8;
  const bf16_t* Arow = Asb + (m0 + cix) * LDST;
  const bf16_t* Bcol = Bsb + cix * LDST;

  f32x4 acc[8];
#pragma unroll
  for (int i = 0; i < 8; ++i) acc[i] = (f32x4){0.f, 0.f, 0.f, 0.f};
  gemm_stripe(Arow, Bcol, koff, acc);  // h @ n_w1a

  __syncthreads();

  for (int i = t; i < 1024; i += 256) {
    int rowl = i >> 4, cc = i & 15;
    int node = node0 + rowl; if (node >= NN) node = NN - 1;
    const float4* p = (const float4*)(agg + (size_t)node * 128 + cc * 8);
    *(bf16x8*)(Asb + rowl * LDST + cc * 8) = cvt8(p[0], p[1]);
  }
  load_B(Bsb, wt + 4 * 16384, t);  // n_w1b_t
  __syncthreads();
  gemm_stripe(Arow, Bcol, koff, acc);  // += agg @ n_w1b

#pragma unroll
  for (int nt = 0; nt < 8; ++nt) {
    int colg = nt * 16 + cix;
    float b1v = n_b1[colg];
#pragma unroll
    for (int rix = 0; rix < 4; ++rix) {
      float u = fsilu(acc[nt][rix] + b1v);
      Asb[(m0 + quad * 4 + rix) * LDST + colg] = (bf16_t)u;
    }
  }
  __syncthreads();
  load_B(Bsb, wt + 5 * 16384, t);  // n_w2t
  __syncthreads();

#pragma unroll
  for (int i = 0; i < 8; ++i) acc[i] = (f32x4){0.f, 0.f, 0.f, 0.f};
  gemm_stripe(Arow, Bcol, koff, acc);  // u @ n_w2

#pragma unroll
  for (int nt = 0; nt < 8; ++nt) {
    int colg = nt * 16 + cix;
    float b2v = n_b2[colg];
#pragma unroll
    for (int rix = 0; rix < 4; ++rix) {
      int node = node0 + m0 + quad * 4 + rix;
      if (node < NN) {
        float ho = h[(size_t)node * 128 + colg] + acc[nt][rix] + b2v;
        out[(size_t)node * 128 + colg] = ho;
      }
    }
  }
}

extern "C" void kernel_launch(void* const* d_in, const int* in_sizes, int n_in,
                              void* d_out, int out_size, void* d_ws, size_t ws_size,
                              hipStream_t stream) {
  const float* h = (const float*)d_in[0];
  const float* x = (const float*)d_in[1];
  const int* ei = (const int*)d_in[2];
  const float* eattr = (const float*)d_in[3];
  const float* e_w1 = (const float*)d_in[4];
  const float* e_b1 = (const float*)d_in[5];
  const float* e_w2 = (const float*)d_in[6];
  const float* e_b2 = (const float*)d_in[7];
  const float* n_w1 = (const float*)d_in[8];
  const float* n_b1 = (const float*)d_in[9];
  const float* n_w2 = (const float*)d_in[10];
  const float* n_b2 = (const float*)d_in[11];
  const float* c_w1 = (const float*)d_in[12];
  const float* c_b1 = (const float*)d_in[13];
  const float* c_w2 = (const float*)d_in[14];
  const float* a_w = (const float*)d_in[15];
  const float* a_b = (const float*)d_in[16];

  float* outp = (float*)d_out;
  float* agg = outp;                           // N*128 f32 (h_out region)
  float* coord_agg = outp + (size_t)NN * 128;  // N*3 f32 (x_out region)

  // ws layout (total ~32.63 MB):
  //   pa 12.8MB | pb 12.8MB | wt 229KB | deg 200KB | curs 200KB | bsum 256B | rec 6.4MB
  char* ws = (char*)d_ws;
  bf16_t* pa = (bf16_t*)(ws + 0);
  bf16_t* pb = (bf16_t*)(ws + 12800000);
  bf16_t* wt = (bf16_t*)(ws + 25600000);   // 229,376 B
  int* deg = (int*)(ws + 25830400);        // 200,000 B
  int* curs = (int*)(ws + 26030464);       // 200,000 B
  int* bsum = (int*)(ws + 26230528);       // 256 B
  int2* rec = (int2*)(ws + 26230784);      // 6,400,000 B -> ends 32,630,784

  const int NSB = (NN + 1023) / 1024;  // 49 scan blocks
  const int NHB = (NE + 255) / 256;    // 3125 hist blocks

  hipMemsetAsync(d_out, 0, (size_t)(NN * 131) * 4, stream);
  hipMemsetAsync((void*)deg, 0, 200000, stream);
  pre_k<<<112 + NHB, 256, 0, stream>>>(e_w1, e_w2, n_w1, n_w2, c_w1, wt, ei, deg);
  prep_k<<<(NN + 63) / 64, 256, 0, stream>>>(h, wt, e_b1, pa, pb);
  scan1_k<<<NSB, 1024, 0, stream>>>(deg, curs, bsum);
  place_k<<<(NE + 255) / 256, 256, 0, stream>>>(ei, eattr, curs, bsum, rec);
  edge_k<<<EGRID, 1024, 0, stream>>>(pa, pb, rec, x, wt, e_w1, e_b2, c_b1, c_w2,
                                     a_w, a_b, agg, coord_agg);
  node_k<<<(NN + 63) / 64, 256, 0, stream>>>(h, x, wt, n_b1, n_b2, deg, outp);
}

// Round 9
// 469.592 us; speedup vs baseline: 1.0031x; 1.0031x over previous
//
#include <hip/hip_runtime.h>

// EGNN layer (round 18): thread the needle — compiler budget 3 waves, HW runs 4.
//  - r17 post-mortem: THIRD spill at min-waves=4 (VGPR pinned 64, FETCH 301MB).
//    Law: launch_bounds(*,4) => compiler pins arch VGPR at 64 for this kernel
//    and spills; launch_bounds(*,3) => allocates the needed 84 cleanly.
//  - This round: launch_bounds(1024, 3) with 16-wave blocks. The 2nd arg is a
//    COMPILER budget hint, not a HW cap. Actual allocation 84+32=116 regs;
//    per-SIMD pool 512 => 4 waves/SIMD fit in HW (4x128=512 even at worst
//    rounding). 16-wave block placeable -> 16 waves/CU TLP + pipeline ILP.
//  - Risk: compiler allocating >96 arch makes the block unplaceable -> clean
//    launch error -> revert. Confidence: same loop allocated 84 at (768,3).
//  - Checks: VGPR=84 (64=repinned), FETCH ~98MB (300=spill), Occ ~38,
//    VALU ~72%, edge ~160-172us.
//  - Kept from r17: scan3 deleted (place_k inline bsum prefix), pre_k fusion,
//    shfl scan1, proportional split, pipeline + hoists + setprio.

#define NN 50000
#define NE 800000
#define LDST 136
#define NW 16
#define NSTRIPE (NE / 16)
#define EGRID 256
#define NWG (EGRID * NW)  // 4096 wave-groups
#define NB 49             // scan blocks (1024 elems each)

typedef __bf16 bf16_t;
typedef __bf16 bf16x8 __attribute__((ext_vector_type(8)));
typedef float f32x4 __attribute__((ext_vector_type(4)));

__device__ __forceinline__ float fsilu(float z) {
  return z * __builtin_amdgcn_rcpf(1.f + __expf(-z));
}
__device__ __forceinline__ float fsigm(float z) {
  return __builtin_amdgcn_rcpf(1.f + __expf(-z));
}

__device__ __forceinline__ void gemm_stripe(const bf16_t* Arow, const bf16_t* Bcol,
                                            int koff, f32x4 acc[8]) {
#pragma unroll
  for (int ks = 0; ks < 4; ++ks) {
    bf16x8 a = *(const bf16x8*)(Arow + ks * 32 + koff);
#pragma unroll
    for (int nt = 0; nt < 8; ++nt) {
      bf16x8 b = *(const bf16x8*)(Bcol + nt * 16 * LDST + ks * 32 + koff);
      acc[nt] = __builtin_amdgcn_mfma_f32_16x16x32_bf16(a, b, acc[nt], 0, 0, 0);
    }
  }
}

__device__ __forceinline__ void load_B(bf16_t* Bsb, const bf16_t* __restrict__ src, int t) {
  for (int i = t; i < 2048; i += 256) {
    int n = i >> 4, cc = i & 15;
    *(bf16x8*)(Bsb + n * LDST + cc * 8) = *(const bf16x8*)(src + n * 128 + cc * 8);
  }
}

__device__ __forceinline__ bf16x8 cvt8(float4 u0, float4 u1) {
  bf16x8 v;
  v[0] = (bf16_t)u0.x; v[1] = (bf16_t)u0.y; v[2] = (bf16_t)u0.z; v[3] = (bf16_t)u0.w;
  v[4] = (bf16_t)u1.x; v[5] = (bf16_t)u1.y; v[6] = (bf16_t)u1.z; v[7] = (bf16_t)u1.w;
  return v;
}

// ---- pre_k: fused weight transpose (blocks 0..111) + degree hist (112..) ----
__global__ __launch_bounds__(256) void pre_k(
    const float* __restrict__ e_w1, const float* __restrict__ e_w2,
    const float* __restrict__ n_w1, const float* __restrict__ n_w2,
    const float* __restrict__ c_w1, bf16_t* __restrict__ wt,
    const int* __restrict__ ei, int* __restrict__ deg) {
  int b = blockIdx.x;
  if (b < 112) {
    int slot = b >> 4;
    int sub = b & 15;
    const float* src;
    switch (slot) {
      case 0: src = e_w1; break;
      case 1: src = e_w1 + 16384; break;
      case 2: src = e_w2; break;
      case 3: src = n_w1; break;
      case 4: src = n_w1 + 16384; break;
      case 5: src = n_w2; break;
      default: src = c_w1; break;
    }
    bf16_t* dst = wt + slot * 16384;
    int base = sub * 1024;
    for (int i = base + threadIdx.x; i < base + 1024; i += 256) {
      int k = i >> 7, n = i & 127;
      dst[n * 128 + k] = (bf16_t)src[k * 128 + n];
    }
  } else {
    int e = (b - 112) * 256 + threadIdx.x;
    if (e < NE) atomicAdd(&deg[ei[e]], 1);
  }
}

// ---- prep: pa = bf16(h@W1a + e_b1), pb = bf16(h@W1b) ----
__global__ __launch_bounds__(256) void prep_k(
    const float* __restrict__ h, const bf16_t* __restrict__ wt,
    const float* __restrict__ e_b1, bf16_t* __restrict__ pa, bf16_t* __restrict__ pb) {
  __shared__ __align__(16) bf16_t Asb[64 * LDST];
  __shared__ __align__(16) bf16_t Bsb[128 * LDST];
  int t = threadIdx.x;
  int node0 = blockIdx.x * 64;
  for (int i = t; i < 1024; i += 256) {
    int rowl = i >> 4, cc = i & 15;
    int node = node0 + rowl; if (node >= NN) node = NN - 1;
    const float4* p = (const float4*)(h + (size_t)node * 128 + cc * 8);
    *(bf16x8*)(Asb + rowl * LDST + cc * 8) = cvt8(p[0], p[1]);
  }
  int lane = t & 63, w = t >> 6;
  int m0 = w * 16, quad = lane >> 4, cix = lane & 15, koff = quad * 8;
  const bf16_t* Arow = Asb + (m0 + cix) * LDST;
  const bf16_t* Bcol = Bsb + cix * LDST;

  bf16_t* outp[2] = {pa, pb};
#pragma unroll
  for (int p = 0; p < 2; ++p) {
    __syncthreads();
    load_B(Bsb, wt + p * 16384, t);
    __syncthreads();
    f32x4 acc[8];
#pragma unroll
    for (int i = 0; i < 8; ++i) acc[i] = (f32x4){0.f, 0.f, 0.f, 0.f};
    gemm_stripe(Arow, Bcol, koff, acc);
#pragma unroll
    for (int nt = 0; nt < 8; ++nt) {
      int colg = nt * 16 + cix;
      float bv = p == 0 ? e_b1[colg] : 0.f;
#pragma unroll
      for (int rix = 0; rix < 4; ++rix) {
        int node = node0 + m0 + quad * 4 + rix;
        if (node < NN) outp[p][(size_t)node * 128 + colg] = (bf16_t)(acc[nt][rix] + bv);
      }
    }
  }
}

// ---- scan1: shfl-based wave scan (2 barriers) ----
__global__ __launch_bounds__(1024) void scan1_k(const int* __restrict__ deg,
                                                int* __restrict__ curs,
                                                int* __restrict__ bsum) {
  __shared__ int wsum[16];
  int t = threadIdx.x;
  int lane = t & 63, wv = t >> 6;
  int i = blockIdx.x * 1024 + t;
  int v = (i < NN) ? deg[i] : 0;
  int sc = v;
#pragma unroll
  for (int off = 1; off < 64; off <<= 1) {
    int u = __shfl_up(sc, off);
    if (lane >= off) sc += u;
  }
  if (lane == 63) wsum[wv] = sc;
  __syncthreads();
  if (wv == 0 && lane < 16) {
    int ws = wsum[lane];
#pragma unroll
    for (int off = 1; off < 16; off <<= 1) {
      int u = __shfl_up(ws, off, 16);
      if ((lane & 15) >= off) ws += u;
    }
    wsum[lane] = ws;
  }
  __syncthreads();
  int base = (wv > 0) ? wsum[wv - 1] : 0;
  int incl = base + sc;
  if (i < NN) curs[i] = incl - v;  // exclusive within block
  if (t == 1023) bsum[blockIdx.x] = incl;
}

// ---- place: scatter packed records; block-prefix of bsum computed inline ----
__global__ __launch_bounds__(256) void place_k(const int* __restrict__ ei,
                                               const float* __restrict__ eattr,
                                               int* __restrict__ curs,
                                               const int* __restrict__ bsum,
                                               int2* __restrict__ rec) {
  __shared__ int pref[64];
  int t = threadIdx.x;
  if (t < 64) {
    int v = (t < NB) ? bsum[t] : 0;
    int sc = v;
#pragma unroll
    for (int off = 1; off < 64; off <<= 1) {
      int u = __shfl_up(sc, off);
      if (t >= off) sc += u;
    }
    pref[t] = sc - v;  // exclusive prefix across scan blocks
  }
  __syncthreads();
  int e = blockIdx.x * 256 + t;
  if (e < NE) {
    int row = ei[e];
    int col = ei[NE + e];
    int pos = atomicAdd(&curs[row], 1) + pref[row >> 10];
    int2 rv;
    rv.x = (int)((unsigned)row * 50000u + (unsigned)col);
    rv.y = __float_as_int(eattr[e]);
    rec[pos] = rv;
  }
}

// ---- edge kernel: 16-wave blocks, compiler budget 3 waves/SIMD, HW runs 4 ----
// Allocation 84 arch + 32 AGPR = 116/wave; 4x116 <= 512/SIMD => block placeable.
__global__ __launch_bounds__(1024, 3) void edge_k(
    const bf16_t* __restrict__ pa, const bf16_t* __restrict__ pb,
    const int2* __restrict__ rec, const float* __restrict__ x,
    const bf16_t* __restrict__ wt, const float* __restrict__ e_w1,
    const float* __restrict__ e_b2, const float* __restrict__ c_b1,
    const float* __restrict__ c_w2, const float* __restrict__ a_w,
    const float* __restrict__ a_b, float* __restrict__ agg,
    float* __restrict__ coord_agg) {
  __shared__ __align__(16) bf16_t Bs2[16384];          // e_w2 (MFMA-chunk layout)
  __shared__ __align__(16) bf16_t Bs6[16384];          // c_w1
  __shared__ __align__(16) float Wr[128];              // w_rad row (loop-invariant)
  __shared__ __align__(16) float We[128];              // w_ea row
  __shared__ __align__(16) bf16_t Ag[NW * 16 * LDST];  // per-wave m stripes

  int t = threadIdx.x;
  const float* wrp = e_w1 + 256 * 128;
  const float* wep = e_w1 + 257 * 128;
  if (t < 128) Wr[t] = wrp[t];
  else if (t < 256) We[t - 128] = wep[t - 128];
  for (int cch = t; cch < 2048; cch += 1024) {
    int nt = cch >> 8, rem = cch & 255, kc = rem >> 4, ci = rem & 15;
    int n = nt * 16 + ci;
    *(bf16x8*)(Bs2 + cch * 8) = *(const bf16x8*)(wt + 2 * 16384 + n * 128 + kc * 8);
    *(bf16x8*)(Bs6 + cch * 8) = *(const bf16x8*)(wt + 6 * 16384 + n * 128 + kc * 8);
  }
  __syncthreads();  // the only barrier

  int lane = t & 63, w = t >> 6;
  int quad = lane >> 4, cix = lane & 15, koff = quad * 8;
  bf16_t* Aw = Ag + w * (16 * LDST);
  float a_bv = a_b[0];

  // loop-invariant per-lane epilogue constants (32 VGPRs; unrolled-index only)
  float eb2v[8], awv8[8], cb1v8[8], cw2v8[8];
#pragma unroll
  for (int nt = 0; nt < 8; ++nt) {
    int colg = nt * 16 + cix;
    eb2v[nt] = e_b2[colg];
    awv8[nt] = a_w[colg];
    cb1v8[nt] = c_b1[colg];
    cw2v8[nt] = c_w2[colg];
  }

  // proportional split: every wave gets 12 or 13 stripes
  int wg = blockIdx.x * NW + w;
  int s0 = (int)(((long long)wg * NSTRIPE) / NWG);
  int s1 = (int)(((long long)(wg + 1) * NSTRIPE) / NWG);

  // carried run state (wave-uniform currow; per-lane col sums)
  int currow = -1;
  int col = 2 * lane;
  float sa = 0.f, sb = 0.f, c0 = 0.f, c1 = 0.f, c2 = 0.f;

  if (s0 < s1) {
    // ---- prologue: fully load stripe s0 into registers ----
    int2 rv = rec[s0 * 16 + cix];
    unsigned rcu = (unsigned)rv.x;
    int r = (int)(rcu / 50000u);
    int c = (int)(rcu - (unsigned)r * 50000u);
    float ea = __int_as_float(rv.y);
    float d0 = x[r * 3 + 0] - x[c * 3 + 0];
    float d1 = x[r * 3 + 1] - x[c * 3 + 1];
    float d2 = x[r * 3 + 2] - x[c * 3 + 2];
    float rad = d0 * d0 + d1 * d1 + d2 * d2;
    bf16x8 pa8[4], pb8[4];
    {
      const bf16_t* par = pa + (size_t)r * 128;
      const bf16_t* pbr = pb + (size_t)c * 128;
#pragma unroll
      for (int ks = 0; ks < 4; ++ks) {
        pa8[ks] = *(const bf16x8*)(par + ks * 32 + koff);
        pb8[ks] = *(const bf16x8*)(pbr + ks * 32 + koff);
      }
    }

#pragma unroll 1
    for (int s = s0; s < s1; ++s) {
      // (1) prefetch next stripe's record
      int sn = (s + 1 < s1) ? s + 1 : s;
      int2 rvn = rec[sn * 16 + cix];

      // (2) GEMM1 fused on CURRENT regs:
      //     z1 = silu(pa[r]+pb[c]+rad*w_rad+ea*w_ea) as A-frag; C = z1 @ e_w2
      f32x4 acc[8];
#pragma unroll
      for (int i = 0; i < 8; ++i) acc[i] = (f32x4){0.f, 0.f, 0.f, 0.f};
#pragma unroll
      for (int ks = 0; ks < 4; ++ks) {
        int kk = ks * 32 + koff;
        float4 wr0 = *(const float4*)(Wr + kk);
        float4 wr1 = *(const float4*)(Wr + kk + 4);
        float4 we0 = *(const float4*)(We + kk);
        float4 we1 = *(const float4*)(We + kk + 4);
        float wrv[8] = {wr0.x, wr0.y, wr0.z, wr0.w, wr1.x, wr1.y, wr1.z, wr1.w};
        float wev[8] = {we0.x, we0.y, we0.z, we0.w, we1.x, we1.y, we1.z, we1.w};
        bf16x8 af;
#pragma unroll
        for (int j = 0; j < 8; ++j) {
          float z = (float)pa8[ks][j] + (float)pb8[ks][j] + rad * wrv[j] + ea * wev[j];
          af[j] = (bf16_t)fsilu(z);
        }
        __builtin_amdgcn_s_setprio(1);
#pragma unroll
        for (int nt = 0; nt < 8; ++nt) {
          bf16x8 b = *(const bf16x8*)(Bs2 + (nt * 256 + (ks * 4 + quad) * 16 + cix) * 8);
          acc[nt] = __builtin_amdgcn_mfma_f32_16x16x32_bf16(af, b, acc[nt], 0, 0, 0);
        }
        __builtin_amdgcn_s_setprio(0);
      }

      // (3) decode NEXT record, issue its gathers now
      unsigned rcn = (unsigned)rvn.x;
      int rn = (int)(rcn / 50000u);
      int cn = (int)(rcn - (unsigned)rn * 50000u);
      float ean = __int_as_float(rvn.y);
      float xr0n = x[rn * 3 + 0], xr1n = x[rn * 3 + 1], xr2n = x[rn * 3 + 2];
      float xc0n = x[cn * 3 + 0], xc1n = x[cn * 3 + 1], xc2n = x[cn * 3 + 2];
      bf16x8 pa8n[4], pb8n[4];
      {
        const bf16_t* parn = pa + (size_t)rn * 128;
        const bf16_t* pbrn = pb + (size_t)cn * 128;
#pragma unroll
        for (int ks = 0; ks < 4; ++ks) {
          pa8n[ks] = *(const bf16x8*)(parn + ks * 32 + koff);
          pb8n[ks] = *(const bf16x8*)(pbrn + ks * 32 + koff);
        }
      }

      // (4) epilogue 1: m = silu(.+b2); att = sigmoid(m.a_w+a_b); m *= att; m -> Aw
      float attp[4] = {0.f, 0.f, 0.f, 0.f};
#pragma unroll
      for (int nt = 0; nt < 8; ++nt) {
        float b2v = eb2v[nt];
        float awv = awv8[nt];
#pragma unroll
        for (int rix = 0; rix < 4; ++rix) {
          float v = fsilu(acc[nt][rix] + b2v);
          acc[nt][rix] = v;
          attp[rix] += v * awv;
        }
      }
      float attv[4];
#pragma unroll
      for (int rix = 0; rix < 4; ++rix) {
        float sv = attp[rix];
        sv += __shfl_xor(sv, 1); sv += __shfl_xor(sv, 2);
        sv += __shfl_xor(sv, 4); sv += __shfl_xor(sv, 8);
        attv[rix] = fsigm(sv + a_bv);
      }
#pragma unroll
      for (int nt = 0; nt < 8; ++nt) {
#pragma unroll
        for (int rix = 0; rix < 4; ++rix) {
          float v = acc[nt][rix] * attv[rix];
          Aw[(quad * 4 + rix) * LDST + nt * 16 + cix] = (bf16_t)v;
        }
      }

      // (5) GEMM2: coord_update = silu(m @ c_w1 + c_b1) . c_w2 (wave-local LDS RAW)
      const bf16_t* Arow = Aw + cix * LDST;
#pragma unroll
      for (int i = 0; i < 8; ++i) acc[i] = (f32x4){0.f, 0.f, 0.f, 0.f};
#pragma unroll
      for (int ks = 0; ks < 4; ++ks) {
        bf16x8 a = *(const bf16x8*)(Arow + ks * 32 + koff);
        __builtin_amdgcn_s_setprio(1);
#pragma unroll
        for (int nt = 0; nt < 8; ++nt) {
          bf16x8 b = *(const bf16x8*)(Bs6 + (nt * 256 + (ks * 4 + quad) * 16 + cix) * 8);
          acc[nt] = __builtin_amdgcn_mfma_f32_16x16x32_bf16(a, b, acc[nt], 0, 0, 0);
        }
        __builtin_amdgcn_s_setprio(0);
      }
      float cup[4] = {0.f, 0.f, 0.f, 0.f};
#pragma unroll
      for (int nt = 0; nt < 8; ++nt) {
        float cb1v = cb1v8[nt];
        float cw2v = cw2v8[nt];
#pragma unroll
        for (int rix = 0; rix < 4; ++rix) {
          cup[rix] += fsilu(acc[nt][rix] + cb1v) * cw2v;
        }
      }
#pragma unroll
      for (int rix = 0; rix < 4; ++rix) {
        float sv = cup[rix];
        sv += __shfl_xor(sv, 1); sv += __shfl_xor(sv, 2);
        sv += __shfl_xor(sv, 4); sv += __shfl_xor(sv, 8);
        cup[rix] = sv;  // all 16 lanes of the quad hold that edge's scalar
      }

      // (6) carried-run merge: flush only on row change (runs span stripes)
#pragma unroll
      for (int e = 0; e < 16; ++e) {
        int rowe = __shfl(r, e);
        if (rowe != currow) {
          if (currow >= 0) {
            atomicAdd(&agg[(size_t)currow * 128 + col], sa);
            atomicAdd(&agg[(size_t)currow * 128 + col + 1], sb);
            if (lane == 0) {
              atomicAdd(&coord_agg[currow * 3 + 0], c0);
              atomicAdd(&coord_agg[currow * 3 + 1], c1);
              atomicAdd(&coord_agg[currow * 3 + 2], c2);
            }
          }
          sa = sb = c0 = c1 = c2 = 0.f;
          currow = rowe;
        }
        float cue = __shfl(cup[e & 3], (e >> 2) * 16);
        float dd0 = __shfl(d0, e), dd1 = __shfl(d1, e), dd2 = __shfl(d2, e);
        c0 += dd0 * cue; c1 += dd1 * cue; c2 += dd2 * cue;
        unsigned u = *(const unsigned*)(Aw + e * LDST + col);
        sa += __uint_as_float(u << 16);
        sb += __uint_as_float(u & 0xffff0000u);
      }

      // (7) rotate: next becomes current
      r = rn; ea = ean;
      d0 = xr0n - xc0n; d1 = xr1n - xc1n; d2 = xr2n - xc2n;
      rad = d0 * d0 + d1 * d1 + d2 * d2;
#pragma unroll
      for (int ks = 0; ks < 4; ++ks) { pa8[ks] = pa8n[ks]; pb8[ks] = pb8n[ks]; }
    }
  }

  // final flush
  if (currow >= 0) {
    atomicAdd(&agg[(size_t)currow * 128 + col], sa);
    atomicAdd(&agg[(size_t)currow * 128 + col + 1], sb);
    if (lane == 0) {
      atomicAdd(&coord_agg[currow * 3 + 0], c0);
      atomicAdd(&coord_agg[currow * 3 + 1], c1);
      atomicAdd(&coord_agg[currow * 3 + 2], c2);
    }
  }
}

// ---- node kernel (in-place on d_out) ----
__global__ __launch_bounds__(256) void node_k(
    const float* __restrict__ h, const float* __restrict__ x,
    const bf16_t* __restrict__ wt, const float* __restrict__ n_b1,
    const float* __restrict__ n_b2, const int* __restrict__ deg,
    float* __restrict__ out) {
  __shared__ __align__(16) bf16_t Asb[64 * LDST];
  __shared__ __align__(16) bf16_t Bsb[128 * LDST];
  int t = threadIdx.x;
  int node0 = blockIdx.x * 64;
  const float* agg = out;
  float* xout = out + (size_t)NN * 128;

  if (t < 192) {
    int node = node0 + t / 3;
    int d = t - (t / 3) * 3;
    if (node < NN) {
      int dv = deg[node];
      float denom = dv > 1 ? (float)dv : 1.f;
      float xo = x[node * 3 + d] + xout[node * 3 + d] / denom;
      xout[node * 3 + d] = xo;
    }
  }

  for (int i = t; i < 1024; i += 256) {
    int rowl = i >> 4, cc = i & 15;
    int node = node0 + rowl; if (node >= NN) node = NN - 1;
    const float4* p = (const float4*)(h + (size_t)node * 128 + cc * 8);
    *(bf16x8*)(Asb + rowl * LDST + cc * 8) = cvt8(p[0], p[1]);
  }
  load_B(Bsb, wt + 3 * 16384, t);  // n_w1a_t
  __syncthreads();

  int lane = t & 63, w = t >> 6;
  int m0 = w * 16, quad = lane >> 4, cix = lane & 15, koff = quad * 8;
  const bf16_t* Arow = Asb + (m0 + cix) * LDST;
  const bf16_t* Bcol = Bsb + cix * LDST;

  f32x4 acc[8];
#pragma unroll
  for (int i = 0; i < 8; ++i) acc[i] = (f32x4){0.f, 0.f, 0.f, 0.f};
  gemm_stripe(Arow, Bcol, koff, acc);  // h @ n_w1a

  __syncthreads();

  for (int i = t; i < 1024; i += 256) {
    int rowl = i >> 4, cc = i & 15;
    int node = node0 + rowl; if (node >= NN) node = NN - 1;
    const float4* p = (const float4*)(agg + (size_t)node * 128 + cc * 8);
    *(bf16x8*)(Asb + rowl * LDST + cc * 8) = cvt8(p[0], p[1]);
  }
  load_B(Bsb, wt + 4 * 16384, t);  // n_w1b_t
  __syncthreads();
  gemm_stripe(Arow, Bcol, koff, acc);  // += agg @ n_w1b

#pragma unroll
  for (int nt = 0; nt < 8; ++nt) {
    int colg = nt * 16 + cix;
    float b1v = n_b1[colg];
#pragma unroll
    for (int rix = 0; rix < 4; ++rix) {
      float u = fsilu(acc[nt][rix] + b1v);
      Asb[(m0 + quad * 4 + rix) * LDST + colg] = (bf16_t)u;
    }
  }
  __syncthreads();
  load_B(Bsb, wt + 5 * 16384, t);  // n_w2t
  __syncthreads();

#pragma unroll
  for (int i = 0; i < 8; ++i) acc[i] = (f32x4){0.f, 0.f, 0.f, 0.f};
  gemm_stripe(Arow, Bcol, koff, acc);  // u @ n_w2

#pragma unroll
  for (int nt = 0; nt < 8; ++nt) {
    int colg = nt * 16 + cix;
    float b2v = n_b2[colg];
#pragma unroll
    for (int rix = 0; rix < 4; ++rix) {
      int node = node0 + m0 + quad * 4 + rix;
      if (node < NN) {
        float ho = h[(size_t)node * 128 + colg] + acc[nt][rix] + b2v;
        out[(size_t)node * 128 + colg] = ho;
      }
    }
  }
}

extern "C" void kernel_launch(void* const* d_in, const int* in_sizes, int n_in,
                              void* d_out, int out_size, void* d_ws, size_t ws_size,
                              hipStream_t stream) {
  const float* h = (const float*)d_in[0];
  const float* x = (const float*)d_in[1];
  const int* ei = (const int*)d_in[2];
  const float* eattr = (const float*)d_in[3];
  const float* e_w1 = (const float*)d_in[4];
  const float* e_b1 = (const float*)d_in[5];
  const float* e_w2 = (const float*)d_in[6];
  const float* e_b2 = (const float*)d_in[7];
  const float* n_w1 = (const float*)d_in[8];
  const float* n_b1 = (const float*)d_in[9];
  const float* n_w2 = (const float*)d_in[10];
  const float* n_b2 = (const float*)d_in[11];
  const float* c_w1 = (const float*)d_in[12];
  const float* c_b1 = (const float*)d_in[13];
  const float* c_w2 = (const float*)d_in[14];
  const float* a_w = (const float*)d_in[15];
  const float* a_b = (const float*)d_in[16];

  float* outp = (float*)d_out;
  float* agg = outp;                           // N*128 f32 (h_out region)
  float* coord_agg = outp + (size_t)NN * 128;  // N*3 f32 (x_out region)

  // ws layout (total ~32.63 MB):
  //   pa 12.8MB | pb 12.8MB | wt 229KB | deg 200KB | curs 200KB | bsum 256B | rec 6.4MB
  char* ws = (char*)d_ws;
  bf16_t* pa = (bf16_t*)(ws + 0);
  bf16_t* pb = (bf16_t*)(ws + 12800000);
  bf16_t* wt = (bf16_t*)(ws + 25600000);   // 229,376 B
  int* deg = (int*)(ws + 25830400);        // 200,000 B
  int* curs = (int*)(ws + 26030464);       // 200,000 B
  int* bsum = (int*)(ws + 26230528);       // 256 B
  int2* rec = (int2*)(ws + 26230784);      // 6,400,000 B -> ends 32,630,784

  const int NSB = (NN + 1023) / 1024;  // 49 scan blocks
  const int NHB = (NE + 255) / 256;    // 3125 hist blocks

  hipMemsetAsync(d_out, 0, (size_t)(NN * 131) * 4, stream);
  hipMemsetAsync((void*)deg, 0, 200000, stream);
  pre_k<<<112 + NHB, 256, 0, stream>>>(e_w1, e_w2, n_w1, n_w2, c_w1, wt, ei, deg);
  prep_k<<<(NN + 63) / 64, 256, 0, stream>>>(h, wt, e_b1, pa, pb);
  scan1_k<<<NSB, 1024, 0, stream>>>(deg, curs, bsum);
  place_k<<<(NE + 255) / 256, 256, 0, stream>>>(ei, eattr, curs, bsum, rec);
  edge_k<<<EGRID, 1024, 0, stream>>>(pa, pb, rec, x, wt, e_w1, e_b2, c_b1, c_w2,
                                     a_w, a_b, agg, coord_agg);
  node_k<<<(NN + 63) / 64, 256, 0, stream>>>(h, x, wt, n_b1, n_b2, deg, outp);
}

// Round 10
// 436.397 us; speedup vs baseline: 1.0794x; 1.0761x over previous
//
#include <hip/hip_runtime.h>

// EGNN layer (round 19): recombine proven halves — r16 edge_k + r18 sort chain.
//  - r18 post-mortem: (1024,3) STILL spilled (VGPR 64, FETCH 302MB). Completed
//    law: a 1024-thread block forces 4 waves/SIMD placement -> 128-reg ceiling
//    -> arch pinned 64 -> pipeline spills, regardless of the launch_bounds
//    min-waves hint. Pipeline and 16-wave blocks are mutually exclusive.
//    (768,3)+pipeline+hoists = 196us is edge_k's proven optimum (r15/r16).
//  - This round: edge_k byte-identical to r16 ((768,3), NW=12, proportional
//    split, pipeline, hoists, setprio). Sort chain kept from r17/r18 (pre_k
//    transpose+hist fusion, shfl scan1, place_k inline bsum prefix, no scan3)
//    — measured others ~228us vs r16's 259us.
//  - Expect: edge VGPR 84 / FETCH ~98MB / ~196us; total ~424-435 (session best).
//  - If confirmed: edge_k at structural floor; remaining target is the ~230us
//    of setup kernels (cooperative hist->scan->place fusion is the main idea).

#define NN 50000
#define NE 800000
#define LDST 136
#define NW 12
#define NSTRIPE (NE / 16)
#define EGRID 256
#define NWG (EGRID * NW)  // 3072 wave-groups
#define NB 49             // scan blocks (1024 elems each)

typedef __bf16 bf16_t;
typedef __bf16 bf16x8 __attribute__((ext_vector_type(8)));
typedef float f32x4 __attribute__((ext_vector_type(4)));

__device__ __forceinline__ float fsilu(float z) {
  return z * __builtin_amdgcn_rcpf(1.f + __expf(-z));
}
__device__ __forceinline__ float fsigm(float z) {
  return __builtin_amdgcn_rcpf(1.f + __expf(-z));
}

__device__ __forceinline__ void gemm_stripe(const bf16_t* Arow, const bf16_t* Bcol,
                                            int koff, f32x4 acc[8]) {
#pragma unroll
  for (int ks = 0; ks < 4; ++ks) {
    bf16x8 a = *(const bf16x8*)(Arow + ks * 32 + koff);
#pragma unroll
    for (int nt = 0; nt < 8; ++nt) {
      bf16x8 b = *(const bf16x8*)(Bcol + nt * 16 * LDST + ks * 32 + koff);
      acc[nt] = __builtin_amdgcn_mfma_f32_16x16x32_bf16(a, b, acc[nt], 0, 0, 0);
    }
  }
}

__device__ __forceinline__ void load_B(bf16_t* Bsb, const bf16_t* __restrict__ src, int t) {
  for (int i = t; i < 2048; i += 256) {
    int n = i >> 4, cc = i & 15;
    *(bf16x8*)(Bsb + n * LDST + cc * 8) = *(const bf16x8*)(src + n * 128 + cc * 8);
  }
}

__device__ __forceinline__ bf16x8 cvt8(float4 u0, float4 u1) {
  bf16x8 v;
  v[0] = (bf16_t)u0.x; v[1] = (bf16_t)u0.y; v[2] = (bf16_t)u0.z; v[3] = (bf16_t)u0.w;
  v[4] = (bf16_t)u1.x; v[5] = (bf16_t)u1.y; v[6] = (bf16_t)u1.z; v[7] = (bf16_t)u1.w;
  return v;
}

// ---- pre_k: fused weight transpose (blocks 0..111) + degree hist (112..) ----
__global__ __launch_bounds__(256) void pre_k(
    const float* __restrict__ e_w1, const float* __restrict__ e_w2,
    const float* __restrict__ n_w1, const float* __restrict__ n_w2,
    const float* __restrict__ c_w1, bf16_t* __restrict__ wt,
    const int* __restrict__ ei, int* __restrict__ deg) {
  int b = blockIdx.x;
  if (b < 112) {
    int slot = b >> 4;
    int sub = b & 15;
    const float* src;
    switch (slot) {
      case 0: src = e_w1; break;
      case 1: src = e_w1 + 16384; break;
      case 2: src = e_w2; break;
      case 3: src = n_w1; break;
      case 4: src = n_w1 + 16384; break;
      case 5: src = n_w2; break;
      default: src = c_w1; break;
    }
    bf16_t* dst = wt + slot * 16384;
    int base = sub * 1024;
    for (int i = base + threadIdx.x; i < base + 1024; i += 256) {
      int k = i >> 7, n = i & 127;
      dst[n * 128 + k] = (bf16_t)src[k * 128 + n];
    }
  } else {
    int e = (b - 112) * 256 + threadIdx.x;
    if (e < NE) atomicAdd(&deg[ei[e]], 1);
  }
}

// ---- prep: pa = bf16(h@W1a + e_b1), pb = bf16(h@W1b) ----
__global__ __launch_bounds__(256) void prep_k(
    const float* __restrict__ h, const bf16_t* __restrict__ wt,
    const float* __restrict__ e_b1, bf16_t* __restrict__ pa, bf16_t* __restrict__ pb) {
  __shared__ __align__(16) bf16_t Asb[64 * LDST];
  __shared__ __align__(16) bf16_t Bsb[128 * LDST];
  int t = threadIdx.x;
  int node0 = blockIdx.x * 64;
  for (int i = t; i < 1024; i += 256) {
    int rowl = i >> 4, cc = i & 15;
    int node = node0 + rowl; if (node >= NN) node = NN - 1;
    const float4* p = (const float4*)(h + (size_t)node * 128 + cc * 8);
    *(bf16x8*)(Asb + rowl * LDST + cc * 8) = cvt8(p[0], p[1]);
  }
  int lane = t & 63, w = t >> 6;
  int m0 = w * 16, quad = lane >> 4, cix = lane & 15, koff = quad * 8;
  const bf16_t* Arow = Asb + (m0 + cix) * LDST;
  const bf16_t* Bcol = Bsb + cix * LDST;

  bf16_t* outp[2] = {pa, pb};
#pragma unroll
  for (int p = 0; p < 2; ++p) {
    __syncthreads();
    load_B(Bsb, wt + p * 16384, t);
    __syncthreads();
    f32x4 acc[8];
#pragma unroll
    for (int i = 0; i < 8; ++i) acc[i] = (f32x4){0.f, 0.f, 0.f, 0.f};
    gemm_stripe(Arow, Bcol, koff, acc);
#pragma unroll
    for (int nt = 0; nt < 8; ++nt) {
      int colg = nt * 16 + cix;
      float bv = p == 0 ? e_b1[colg] : 0.f;
#pragma unroll
      for (int rix = 0; rix < 4; ++rix) {
        int node = node0 + m0 + quad * 4 + rix;
        if (node < NN) outp[p][(size_t)node * 128 + colg] = (bf16_t)(acc[nt][rix] + bv);
      }
    }
  }
}

// ---- scan1: shfl-based wave scan (2 barriers) ----
__global__ __launch_bounds__(1024) void scan1_k(const int* __restrict__ deg,
                                                int* __restrict__ curs,
                                                int* __restrict__ bsum) {
  __shared__ int wsum[16];
  int t = threadIdx.x;
  int lane = t & 63, wv = t >> 6;
  int i = blockIdx.x * 1024 + t;
  int v = (i < NN) ? deg[i] : 0;
  int sc = v;
#pragma unroll
  for (int off = 1; off < 64; off <<= 1) {
    int u = __shfl_up(sc, off);
    if (lane >= off) sc += u;
  }
  if (lane == 63) wsum[wv] = sc;
  __syncthreads();
  if (wv == 0 && lane < 16) {
    int ws = wsum[lane];
#pragma unroll
    for (int off = 1; off < 16; off <<= 1) {
      int u = __shfl_up(ws, off, 16);
      if ((lane & 15) >= off) ws += u;
    }
    wsum[lane] = ws;
  }
  __syncthreads();
  int base = (wv > 0) ? wsum[wv - 1] : 0;
  int incl = base + sc;
  if (i < NN) curs[i] = incl - v;  // exclusive within block
  if (t == 1023) bsum[blockIdx.x] = incl;
}

// ---- place: scatter packed records; block-prefix of bsum computed inline ----
__global__ __launch_bounds__(256) void place_k(const int* __restrict__ ei,
                                               const float* __restrict__ eattr,
                                               int* __restrict__ curs,
                                               const int* __restrict__ bsum,
                                               int2* __restrict__ rec) {
  __shared__ int pref[64];
  int t = threadIdx.x;
  if (t < 64) {
    int v = (t < NB) ? bsum[t] : 0;
    int sc = v;
#pragma unroll
    for (int off = 1; off < 64; off <<= 1) {
      int u = __shfl_up(sc, off);
      if (t >= off) sc += u;
    }
    pref[t] = sc - v;  // exclusive prefix across scan blocks
  }
  __syncthreads();
  int e = blockIdx.x * 256 + t;
  if (e < NE) {
    int row = ei[e];
    int col = ei[NE + e];
    int pos = atomicAdd(&curs[row], 1) + pref[row >> 10];
    int2 rv;
    rv.x = (int)((unsigned)row * 50000u + (unsigned)col);
    rv.y = __float_as_int(eattr[e]);
    rec[pos] = rv;
  }
}

// ---- edge kernel: (768,3), NW=12 — the proven optimum (r15/r16, 196us) ----
__global__ __launch_bounds__(768, 3) void edge_k(
    const bf16_t* __restrict__ pa, const bf16_t* __restrict__ pb,
    const int2* __restrict__ rec, const float* __restrict__ x,
    const bf16_t* __restrict__ wt, const float* __restrict__ e_w1,
    const float* __restrict__ e_b2, const float* __restrict__ c_b1,
    const float* __restrict__ c_w2, const float* __restrict__ a_w,
    const float* __restrict__ a_b, float* __restrict__ agg,
    float* __restrict__ coord_agg) {
  __shared__ __align__(16) bf16_t Bs2[16384];          // e_w2 (MFMA-chunk layout)
  __shared__ __align__(16) bf16_t Bs6[16384];          // c_w1
  __shared__ __align__(16) float Wr[128];              // w_rad row (loop-invariant)
  __shared__ __align__(16) float We[128];              // w_ea row
  __shared__ __align__(16) bf16_t Ag[NW * 16 * LDST];  // per-wave m stripes

  int t = threadIdx.x;
  const float* wrp = e_w1 + 256 * 128;
  const float* wep = e_w1 + 257 * 128;
  if (t < 128) Wr[t] = wrp[t];
  else if (t < 256) We[t - 128] = wep[t - 128];
  for (int cch = t; cch < 2048; cch += 768) {
    int nt = cch >> 8, rem = cch & 255, kc = rem >> 4, ci = rem & 15;
    int n = nt * 16 + ci;
    *(bf16x8*)(Bs2 + cch * 8) = *(const bf16x8*)(wt + 2 * 16384 + n * 128 + kc * 8);
    *(bf16x8*)(Bs6 + cch * 8) = *(const bf16x8*)(wt + 6 * 16384 + n * 128 + kc * 8);
  }
  __syncthreads();  // the only barrier

  int lane = t & 63, w = t >> 6;
  int quad = lane >> 4, cix = lane & 15, koff = quad * 8;
  bf16_t* Aw = Ag + w * (16 * LDST);
  float a_bv = a_b[0];

  // loop-invariant per-lane epilogue constants (32 VGPRs; unrolled-index only)
  float eb2v[8], awv8[8], cb1v8[8], cw2v8[8];
#pragma unroll
  for (int nt = 0; nt < 8; ++nt) {
    int colg = nt * 16 + cix;
    eb2v[nt] = e_b2[colg];
    awv8[nt] = a_w[colg];
    cb1v8[nt] = c_b1[colg];
    cw2v8[nt] = c_w2[colg];
  }

  // proportional split: every wave gets 16 or 17 stripes
  int wg = blockIdx.x * NW + w;
  int s0 = (int)(((long long)wg * NSTRIPE) / NWG);
  int s1 = (int)(((long long)(wg + 1) * NSTRIPE) / NWG);

  // carried run state (wave-uniform currow; per-lane col sums)
  int currow = -1;
  int col = 2 * lane;
  float sa = 0.f, sb = 0.f, c0 = 0.f, c1 = 0.f, c2 = 0.f;

  if (s0 < s1) {
    // ---- prologue: fully load stripe s0 into registers ----
    int2 rv = rec[s0 * 16 + cix];
    unsigned rcu = (unsigned)rv.x;
    int r = (int)(rcu / 50000u);
    int c = (int)(rcu - (unsigned)r * 50000u);
    float ea = __int_as_float(rv.y);
    float d0 = x[r * 3 + 0] - x[c * 3 + 0];
    float d1 = x[r * 3 + 1] - x[c * 3 + 1];
    float d2 = x[r * 3 + 2] - x[c * 3 + 2];
    float rad = d0 * d0 + d1 * d1 + d2 * d2;
    bf16x8 pa8[4], pb8[4];
    {
      const bf16_t* par = pa + (size_t)r * 128;
      const bf16_t* pbr = pb + (size_t)c * 128;
#pragma unroll
      for (int ks = 0; ks < 4; ++ks) {
        pa8[ks] = *(const bf16x8*)(par + ks * 32 + koff);
        pb8[ks] = *(const bf16x8*)(pbr + ks * 32 + koff);
      }
    }

#pragma unroll 1
    for (int s = s0; s < s1; ++s) {
      // (1) prefetch next stripe's record
      int sn = (s + 1 < s1) ? s + 1 : s;
      int2 rvn = rec[sn * 16 + cix];

      // (2) GEMM1 fused on CURRENT regs:
      //     z1 = silu(pa[r]+pb[c]+rad*w_rad+ea*w_ea) as A-frag; C = z1 @ e_w2
      f32x4 acc[8];
#pragma unroll
      for (int i = 0; i < 8; ++i) acc[i] = (f32x4){0.f, 0.f, 0.f, 0.f};
#pragma unroll
      for (int ks = 0; ks < 4; ++ks) {
        int kk = ks * 32 + koff;
        float4 wr0 = *(const float4*)(Wr + kk);
        float4 wr1 = *(const float4*)(Wr + kk + 4);
        float4 we0 = *(const float4*)(We + kk);
        float4 we1 = *(const float4*)(We + kk + 4);
        float wrv[8] = {wr0.x, wr0.y, wr0.z, wr0.w, wr1.x, wr1.y, wr1.z, wr1.w};
        float wev[8] = {we0.x, we0.y, we0.z, we0.w, we1.x, we1.y, we1.z, we1.w};
        bf16x8 af;
#pragma unroll
        for (int j = 0; j < 8; ++j) {
          float z = (float)pa8[ks][j] + (float)pb8[ks][j] + rad * wrv[j] + ea * wev[j];
          af[j] = (bf16_t)fsilu(z);
        }
        __builtin_amdgcn_s_setprio(1);
#pragma unroll
        for (int nt = 0; nt < 8; ++nt) {
          bf16x8 b = *(const bf16x8*)(Bs2 + (nt * 256 + (ks * 4 + quad) * 16 + cix) * 8);
          acc[nt] = __builtin_amdgcn_mfma_f32_16x16x32_bf16(af, b, acc[nt], 0, 0, 0);
        }
        __builtin_amdgcn_s_setprio(0);
      }

      // (3) decode NEXT record, issue its gathers now
      unsigned rcn = (unsigned)rvn.x;
      int rn = (int)(rcn / 50000u);
      int cn = (int)(rcn - (unsigned)rn * 50000u);
      float ean = __int_as_float(rvn.y);
      float xr0n = x[rn * 3 + 0], xr1n = x[rn * 3 + 1], xr2n = x[rn * 3 + 2];
      float xc0n = x[cn * 3 + 0], xc1n = x[cn * 3 + 1], xc2n = x[cn * 3 + 2];
      bf16x8 pa8n[4], pb8n[4];
      {
        const bf16_t* parn = pa + (size_t)rn * 128;
        const bf16_t* pbrn = pb + (size_t)cn * 128;
#pragma unroll
        for (int ks = 0; ks < 4; ++ks) {
          pa8n[ks] = *(const bf16x8*)(parn + ks * 32 + koff);
          pb8n[ks] = *(const bf16x8*)(pbrn + ks * 32 + koff);
        }
      }

      // (4) epilogue 1: m = silu(.+b2); att = sigmoid(m.a_w+a_b); m *= att; m -> Aw
      float attp[4] = {0.f, 0.f, 0.f, 0.f};
#pragma unroll
      for (int nt = 0; nt < 8; ++nt) {
        float b2v = eb2v[nt];
        float awv = awv8[nt];
#pragma unroll
        for (int rix = 0; rix < 4; ++rix) {
          float v = fsilu(acc[nt][rix] + b2v);
          acc[nt][rix] = v;
          attp[rix] += v * awv;
        }
      }
      float attv[4];
#pragma unroll
      for (int rix = 0; rix < 4; ++rix) {
        float sv = attp[rix];
        sv += __shfl_xor(sv, 1); sv += __shfl_xor(sv, 2);
        sv += __shfl_xor(sv, 4); sv += __shfl_xor(sv, 8);
        attv[rix] = fsigm(sv + a_bv);
      }
#pragma unroll
      for (int nt = 0; nt < 8; ++nt) {
#pragma unroll
        for (int rix = 0; rix < 4; ++rix) {
          float v = acc[nt][rix] * attv[rix];
          Aw[(quad * 4 + rix) * LDST + nt * 16 + cix] = (bf16_t)v;
        }
      }

      // (5) GEMM2: coord_update = silu(m @ c_w1 + c_b1) . c_w2 (wave-local LDS RAW)
      const bf16_t* Arow = Aw + cix * LDST;
#pragma unroll
      for (int i = 0; i < 8; ++i) acc[i] = (f32x4){0.f, 0.f, 0.f, 0.f};
#pragma unroll
      for (int ks = 0; ks < 4; ++ks) {
        bf16x8 a = *(const bf16x8*)(Arow + ks * 32 + koff);
        __builtin_amdgcn_s_setprio(1);
#pragma unroll
        for (int nt = 0; nt < 8; ++nt) {
          bf16x8 b = *(const bf16x8*)(Bs6 + (nt * 256 + (ks * 4 + quad) * 16 + cix) * 8);
          acc[nt] = __builtin_amdgcn_mfma_f32_16x16x32_bf16(a, b, acc[nt], 0, 0, 0);
        }
        __builtin_amdgcn_s_setprio(0);
      }
      float cup[4] = {0.f, 0.f, 0.f, 0.f};
#pragma unroll
      for (int nt = 0; nt < 8; ++nt) {
        float cb1v = cb1v8[nt];
        float cw2v = cw2v8[nt];
#pragma unroll
        for (int rix = 0; rix < 4; ++rix) {
          cup[rix] += fsilu(acc[nt][rix] + cb1v) * cw2v;
        }
      }
#pragma unroll
      for (int rix = 0; rix < 4; ++rix) {
        float sv = cup[rix];
        sv += __shfl_xor(sv, 1); sv += __shfl_xor(sv, 2);
        sv += __shfl_xor(sv, 4); sv += __shfl_xor(sv, 8);
        cup[rix] = sv;  // all 16 lanes of the quad hold that edge's scalar
      }

      // (6) carried-run merge: flush only on row change (runs span stripes)
#pragma unroll
      for (int e = 0; e < 16; ++e) {
        int rowe = __shfl(r, e);
        if (rowe != currow) {
          if (currow >= 0) {
            atomicAdd(&agg[(size_t)currow * 128 + col], sa);
            atomicAdd(&agg[(size_t)currow * 128 + col + 1], sb);
            if (lane == 0) {
              atomicAdd(&coord_agg[currow * 3 + 0], c0);
              atomicAdd(&coord_agg[currow * 3 + 1], c1);
              atomicAdd(&coord_agg[currow * 3 + 2], c2);
            }
          }
          sa = sb = c0 = c1 = c2 = 0.f;
          currow = rowe;
        }
        float cue = __shfl(cup[e & 3], (e >> 2) * 16);
        float dd0 = __shfl(d0, e), dd1 = __shfl(d1, e), dd2 = __shfl(d2, e);
        c0 += dd0 * cue; c1 += dd1 * cue; c2 += dd2 * cue;
        unsigned u = *(const unsigned*)(Aw + e * LDST + col);
        sa += __uint_as_float(u << 16);
        sb += __uint_as_float(u & 0xffff0000u);
      }

      // (7) rotate: next becomes current
      r = rn; ea = ean;
      d0 = xr0n - xc0n; d1 = xr1n - xc1n; d2 = xr2n - xc2n;
      rad = d0 * d0 + d1 * d1 + d2 * d2;
#pragma unroll
      for (int ks = 0; ks < 4; ++ks) { pa8[ks] = pa8n[ks]; pb8[ks] = pb8n[ks]; }
    }
  }

  // final flush
  if (currow >= 0) {
    atomicAdd(&agg[(size_t)currow * 128 + col], sa);
    atomicAdd(&agg[(size_t)currow * 128 + col + 1], sb);
    if (lane == 0) {
      atomicAdd(&coord_agg[currow * 3 + 0], c0);
      atomicAdd(&coord_agg[currow * 3 + 1], c1);
      atomicAdd(&coord_agg[currow * 3 + 2], c2);
    }
  }
}

// ---- node kernel (in-place on d_out) ----
__global__ __launch_bounds__(256) void node_k(
    const float* __restrict__ h, const float* __restrict__ x,
    const bf16_t* __restrict__ wt, const float* __restrict__ n_b1,
    const float* __restrict__ n_b2, const int* __restrict__ deg,
    float* __restrict__ out) {
  __shared__ __align__(16) bf16_t Asb[64 * LDST];
  __shared__ __align__(16) bf16_t Bsb[128 * LDST];
  int t = threadIdx.x;
  int node0 = blockIdx.x * 64;
  const float* agg = out;
  float* xout = out + (size_t)NN * 128;

  if (t < 192) {
    int node = node0 + t / 3;
    int d = t - (t / 3) * 3;
    if (node < NN) {
      int dv = deg[node];
      float denom = dv > 1 ? (float)dv : 1.f;
      float xo = x[node * 3 + d] + xout[node * 3 + d] / denom;
      xout[node * 3 + d] = xo;
    }
  }

  for (int i = t; i < 1024; i += 256) {
    int rowl = i >> 4, cc = i & 15;
    int node = node0 + rowl; if (node >= NN) node = NN - 1;
    const float4* p = (const float4*)(h + (size_t)node * 128 + cc * 8);
    *(bf16x8*)(Asb + rowl * LDST + cc * 8) = cvt8(p[0], p[1]);
  }
  load_B(Bsb, wt + 3 * 16384, t);  // n_w1a_t
  __syncthreads();

  int lane = t & 63, w = t >> 6;
  int m0 = w * 16, quad = lane >> 4, cix = lane & 15, koff = quad * 8;
  const bf16_t* Arow = Asb + (m0 + cix) * LDST;
  const bf16_t* Bcol = Bsb + cix * LDST;

  f32x4 acc[8];
#pragma unroll
  for (int i = 0; i < 8; ++i) acc[i] = (f32x4){0.f, 0.f, 0.f, 0.f};
  gemm_stripe(Arow, Bcol, koff, acc);  // h @ n_w1a

  __syncthreads();

  for (int i = t; i < 1024; i += 256) {
    int rowl = i >> 4, cc = i & 15;
    int node = node0 + rowl; if (node >= NN) node = NN - 1;
    const float4* p = (const float4*)(agg + (size_t)node * 128 + cc * 8);
    *(bf16x8*)(Asb + rowl * LDST + cc * 8) = cvt8(p[0], p[1]);
  }
  load_B(Bsb, wt + 4 * 16384, t);  // n_w1b_t
  __syncthreads();
  gemm_stripe(Arow, Bcol, koff, acc);  // += agg @ n_w1b

#pragma unroll
  for (int nt = 0; nt < 8; ++nt) {
    int colg = nt * 16 + cix;
    float b1v = n_b1[colg];
#pragma unroll
    for (int rix = 0; rix < 4; ++rix) {
      float u = fsilu(acc[nt][rix] + b1v);
      Asb[(m0 + quad * 4 + rix) * LDST + colg] = (bf16_t)u;
    }
  }
  __syncthreads();
  load_B(Bsb, wt + 5 * 16384, t);  // n_w2t
  __syncthreads();

#pragma unroll
  for (int i = 0; i < 8; ++i) acc[i] = (f32x4){0.f, 0.f, 0.f, 0.f};
  gemm_stripe(Arow, Bcol, koff, acc);  // u @ n_w2

#pragma unroll
  for (int nt = 0; nt < 8; ++nt) {
    int colg = nt * 16 + cix;
    float b2v = n_b2[colg];
#pragma unroll
    for (int rix = 0; rix < 4; ++rix) {
      int node = node0 + m0 + quad * 4 + rix;
      if (node < NN) {
        float ho = h[(size_t)node * 128 + colg] + acc[nt][rix] + b2v;
        out[(size_t)node * 128 + colg] = ho;
      }
    }
  }
}

extern "C" void kernel_launch(void* const* d_in, const int* in_sizes, int n_in,
                              void* d_out, int out_size, void* d_ws, size_t ws_size,
                              hipStream_t stream) {
  const float* h = (const float*)d_in[0];
  const float* x = (const float*)d_in[1];
  const int* ei = (const int*)d_in[2];
  const float* eattr = (const float*)d_in[3];
  const float* e_w1 = (const float*)d_in[4];
  const float* e_b1 = (const float*)d_in[5];
  const float* e_w2 = (const float*)d_in[6];
  const float* e_b2 = (const float*)d_in[7];
  const float* n_w1 = (const float*)d_in[8];
  const float* n_b1 = (const float*)d_in[9];
  const float* n_w2 = (const float*)d_in[10];
  const float* n_b2 = (const float*)d_in[11];
  const float* c_w1 = (const float*)d_in[12];
  const float* c_b1 = (const float*)d_in[13];
  const float* c_w2 = (const float*)d_in[14];
  const float* a_w = (const float*)d_in[15];
  const float* a_b = (const float*)d_in[16];

  float* outp = (float*)d_out;
  float* agg = outp;                           // N*128 f32 (h_out region)
  float* coord_agg = outp + (size_t)NN * 128;  // N*3 f32 (x_out region)

  // ws layout (total ~32.63 MB):
  //   pa 12.8MB | pb 12.8MB | wt 229KB | deg 200KB | curs 200KB | bsum 256B | rec 6.4MB
  char* ws = (char*)d_ws;
  bf16_t* pa = (bf16_t*)(ws + 0);
  bf16_t* pb = (bf16_t*)(ws + 12800000);
  bf16_t* wt = (bf16_t*)(ws + 25600000);   // 229,376 B
  int* deg = (int*)(ws + 25830400);        // 200,000 B
  int* curs = (int*)(ws + 26030464);       // 200,000 B
  int* bsum = (int*)(ws + 26230528);       // 256 B
  int2* rec = (int2*)(ws + 26230784);      // 6,400,000 B -> ends 32,630,784

  const int NSB = (NN + 1023) / 1024;  // 49 scan blocks
  const int NHB = (NE + 255) / 256;    // 3125 hist blocks

  hipMemsetAsync(d_out, 0, (size_t)(NN * 131) * 4, stream);
  hipMemsetAsync((void*)deg, 0, 200000, stream);
  pre_k<<<112 + NHB, 256, 0, stream>>>(e_w1, e_w2, n_w1, n_w2, c_w1, wt, ei, deg);
  prep_k<<<(NN + 63) / 64, 256, 0, stream>>>(h, wt, e_b1, pa, pb);
  scan1_k<<<NSB, 1024, 0, stream>>>(deg, curs, bsum);
  place_k<<<(NE + 255) / 256, 256, 0, stream>>>(ei, eattr, curs, bsum, rec);
  edge_k<<<EGRID, 768, 0, stream>>>(pa, pb, rec, x, wt, e_w1, e_b2, c_b1, c_w2,
                                    a_w, a_b, agg, coord_agg);
  node_k<<<(NN + 63) / 64, 256, 0, stream>>>(h, x, wt, n_b1, n_b2, deg, outp);
}